// Round 6
// baseline (252.362 us; speedup 1.0000x reference)
//
#include <hip/hip_runtime.h>
#include <hip/hip_bf16.h>
#include <stdint.h>

#define T_TOKENS 8192
#define D_DIM    1024
#define NE       10
#define NT       8
#define SEG      2048   // padded per-expert list capacity (actual ~1638+-40)

typedef unsigned short u16;
typedef __attribute__((ext_vector_type(8))) __bf16 bf16x8;
typedef __attribute__((ext_vector_type(4))) float  f32x4;
typedef __attribute__((ext_vector_type(8))) unsigned short u16x8;
typedef __attribute__((ext_vector_type(4))) unsigned short u16x4;

static __device__ __forceinline__ u16 f32_to_bf16(float f) {
  union { float f; uint32_t u; } v; v.f = f;
  uint32_t u = v.u;
  return (u16)((u + 0x7fffu + ((u >> 16) & 1u)) >> 16);
}
static __device__ __forceinline__ float bf16_to_f32(u16 u) {
  union { uint32_t u; float f; } v; v.u = ((uint32_t)u) << 16; return v.f;
}

// ---------------------------------------------------------------------------
// Kernel 1: prep = gate + weight-transpose fused (independent work, one
// dispatch). blockIdx.x < 512 -> gate role (16 tokens/block); else 64x64
// fp32->bf16 transpose tile of W. LDS union 41KB.
// ---------------------------------------------------------------------------
union PrepShared {
  struct { float gws[NE * D_DIM]; float gbs[NE]; int se[32]; float swt[32]; } g;
  struct { float tile[64][65]; } t;
};

__global__ __launch_bounds__(256) void prep_kernel(
    const float* __restrict__ x, const float* __restrict__ gw,
    const float* __restrict__ gb, const float* __restrict__ W,
    u16* __restrict__ xb, u16* __restrict__ wT,
    int* __restrict__ cnt, int* __restrict__ tokList,
    int* __restrict__ revIdx, float* __restrict__ revW) {
  __shared__ PrepShared sh;
  int tid = threadIdx.x;

  if (blockIdx.x >= 512) {
    // ---- transpose role: W [e][d][j] fp32 -> wT [e][j][d] bf16 ----
    int tb = blockIdx.x - 512;
    int e  = tb >> 8;
    int rem = tb & 255;
    int k0 = (rem >> 4) * 64;
    int n0 = (rem & 15) * 64;
    int c  = tid & 63;
    int r0 = tid >> 6;
    const float* We = W + ((size_t)e << 20);
#pragma unroll
    for (int rr = 0; rr < 16; ++rr) {
      int r = rr * 4 + r0;
      sh.t.tile[c][r] = We[(size_t)(k0 + r) * 1024 + n0 + c];
    }
    __syncthreads();
    u16* wTe = wT + ((size_t)e << 20);
#pragma unroll
    for (int rr = 0; rr < 16; ++rr) {
      int n = rr * 4 + r0;
      wTe[(size_t)(n0 + n) * 1024 + k0 + c] = f32_to_bf16(sh.t.tile[n][c]);
    }
    return;
  }

  // ---- gate role: top-2 (strict > scan = lax.top_k tie-break) ----
  {
    const f32x4* g4 = (const f32x4*)gw;
    f32x4* s4 = (f32x4*)sh.g.gws;
    for (int i = tid; i < NE * D_DIM / 4; i += 256) s4[i] = g4[i];
  }
  if (tid < NE) sh.g.gbs[tid] = gb[tid];
  __syncthreads();
  int lane = tid & 63;
  int wv   = tid >> 6;
  const f32x4* gws4 = (const f32x4*)sh.g.gws;
  for (int it = 0; it < 4; ++it) {
    int slot = wv * 4 + it;
    int t = blockIdx.x * 16 + slot;
    const f32x4* xr4 = (const f32x4*)(x + (size_t)t * D_DIM);
    f32x4 xv[4];
#pragma unroll
    for (int jj = 0; jj < 4; ++jj) xv[jj] = xr4[lane + 64 * jj];
    u16x4* xbr = (u16x4*)(xb + (size_t)t * D_DIM);
#pragma unroll
    for (int jj = 0; jj < 4; ++jj) {
      u16x4 pk;
#pragma unroll
      for (int k = 0; k < 4; ++k) pk[k] = f32_to_bf16(xv[jj][k]);
      xbr[lane + 64 * jj] = pk;
    }
    float logit[NE];
#pragma unroll
    for (int e = 0; e < NE; ++e) {
      float a = 0.f;
#pragma unroll
      for (int jj = 0; jj < 4; ++jj) {
        f32x4 gv = gws4[e * 256 + lane + 64 * jj];
#pragma unroll
        for (int k = 0; k < 4; ++k) a = fmaf(xv[jj][k], gv[k], a);
      }
#pragma unroll
      for (int off = 32; off >= 1; off >>= 1) a += __shfl_xor(a, off);
      logit[e] = a + sh.g.gbs[e];
    }
    float mx = logit[0];
#pragma unroll
    for (int e = 1; e < NE; ++e) mx = fmaxf(mx, logit[e]);
    float p[NE]; float s = 0.f;
#pragma unroll
    for (int e = 0; e < NE; ++e) { p[e] = expf(logit[e] - mx); s += p[e]; }
    int e0 = 0; float b0 = p[0];
#pragma unroll
    for (int e = 1; e < NE; ++e) if (p[e] > b0) { b0 = p[e]; e0 = e; }
    int e1 = -1; float b1 = -1.f;
#pragma unroll
    for (int e = 0; e < NE; ++e) if (e != e0 && p[e] > b1) { b1 = p[e]; e1 = e; }
    float w0 = b0 / s, w1 = b1 / s;
    float tw0 = (e0 < NT) ? w0 : 0.f;
    float tw1 = (e1 < NT) ? w1 : 0.f;
    float denom = tw0 + tw1;
    float nw0 = 0.f, nw1 = 0.f;
    if (denom > 0.f) { nw0 = tw0 / denom; nw1 = tw1 / denom; }
    if (lane == 0) {
      sh.g.se[slot * 2]     = (e0 < NT) ? e0 : -1;  sh.g.swt[slot * 2]     = nw0;
      sh.g.se[slot * 2 + 1] = (e1 < NT) ? e1 : -1;  sh.g.swt[slot * 2 + 1] = nw1;
      if (e0 >= NT) { revIdx[t * 2]     = -1; revW[t * 2]     = 0.f; }
      if (e1 >= NT) { revIdx[t * 2 + 1] = -1; revW[t * 2 + 1] = 0.f; }
    }
  }
  __syncthreads();
  // compaction: thread e<8 scans 32 (token,slot) entries; one padded atomic.
  if (tid < NT) {
    int e = tid, c = 0;
    for (int i = 0; i < 32; ++i) c += (sh.g.se[i] == e);
    if (c > 0) {
      int base = atomicAdd(&cnt[e * 32], c);
      int j = 0;
      for (int i = 0; i < 32; ++i) {
        if (sh.g.se[i] == e) {
          int tt  = blockIdx.x * 16 + (i >> 1);
          int pos = base + j;
          tokList[e * SEG + pos]   = tt;
          revIdx[tt * 2 + (i & 1)] = e * SEG + pos;
          revW[tt * 2 + (i & 1)]   = sh.g.swt[i];
          ++j;
        }
      }
    }
  }
}

// ---------------------------------------------------------------------------
// Kernel 2: per-expert gathered GEMM — DIRECT-FROM-GLOBAL fragments.
// R6 rationale: R4/R5's DMA+barrier loop ran ~4100 cyc/block-iter vs m97's
// ~736 for the same traffic — the barrier machinery, not load latency, was
// the cost (lookahead-2 gained only 9%). B (2MB) + gathered A (~3.3MB) are
// XCD-L2-resident (grid x=expert -> XCD affinity, R4: FETCH 74->28MB), and
// the 16x16x32 fragment layout A[m=lane&15][k=quad*8+j] is 16B-contiguous
// per lane in global memory -> load fragments straight into VGPRs with
// global_load_dwordx4. No LDS tiles, no s_barrier in the K-loop; register
// double-buffer gives 1 iter of lookahead; duplicate frag reads between
// wave pairs hit L1. Over-read of <=64B past row end on the final prefetch
// stays inside d_ws (xb->wT->ybuf adjacency) and is never consumed.
// Epilogue: raw (acc+bias) -> bf16 ybuf, plain stores, no races.
// ---------------------------------------------------------------------------
__global__ __launch_bounds__(256) void moe_gemm(
    const u16* __restrict__ xb, const u16* __restrict__ wT,
    const int* __restrict__ cnt, const int* __restrict__ tokList,
    const float* __restrict__ eb, u16* __restrict__ ybuf) {
  int e  = blockIdx.x;
  int c  = cnt[e * 32];
  int m0 = blockIdx.z * 128;
  if (m0 >= c) return;
  int n0 = blockIdx.y * 128;
  __shared__ int tokS[128];
  int tid = threadIdx.x;
  if (tid < 128) {
    int gm = m0 + tid;
    tokS[tid] = (gm < c) ? tokList[e * SEG + gm] : tokList[e * SEG];
  }
  __syncthreads();
  int lane = tid & 63;
  int wv   = tid >> 6;
  int wm = wv >> 1, wn = wv & 1;
  int lrow = lane & 15;            // fragment row (A) / col (B)
  int q    = lane >> 4;            // k-quad: lane holds k = q*8 .. q*8+7
  // 32-bit element offsets (SGPR-base + voffset addressing)
  const u16* wTe = wT + ((size_t)e << 20);
  int aO[4], bO[4];
#pragma unroll
  for (int mt = 0; mt < 4; ++mt)
    aO[mt] = tokS[wm * 64 + mt * 16 + lrow] * 1024 + q * 8;
#pragma unroll
  for (int nt = 0; nt < 4; ++nt)
    bO[nt] = (n0 + wn * 64 + nt * 16 + lrow) * 1024 + q * 8;

  f32x4 acc[4][4];
#pragma unroll
  for (int i = 0; i < 4; ++i)
#pragma unroll
    for (int j = 0; j < 4; ++j) acc[i][j] = (f32x4){0.f, 0.f, 0.f, 0.f};

  bf16x8 aC[4], bC[4], aN[4], bN[4];
#pragma unroll
  for (int mt = 0; mt < 4; ++mt) aC[mt] = *(const bf16x8*)(xb + aO[mt]);
#pragma unroll
  for (int nt = 0; nt < 4; ++nt) bC[nt] = *(const bf16x8*)(wTe + bO[nt]);

#pragma unroll 1
  for (int kb = 0; kb < 1024; kb += 64) {
    // phase 0: prefetch kb+32 into N, compute on C (@ kb)
#pragma unroll
    for (int mt = 0; mt < 4; ++mt) aN[mt] = *(const bf16x8*)(xb + aO[mt] + kb + 32);
#pragma unroll
    for (int nt = 0; nt < 4; ++nt) bN[nt] = *(const bf16x8*)(wTe + bO[nt] + kb + 32);
#pragma unroll
    for (int mt = 0; mt < 4; ++mt)
#pragma unroll
      for (int nt = 0; nt < 4; ++nt)
        acc[mt][nt] = __builtin_amdgcn_mfma_f32_16x16x32_bf16(
            aC[mt], bC[nt], acc[mt][nt], 0, 0, 0);
    // phase 1: prefetch kb+64 into C (last iter over-reads 64B, discarded),
    // compute on N (@ kb+32)
#pragma unroll
    for (int mt = 0; mt < 4; ++mt) aC[mt] = *(const bf16x8*)(xb + aO[mt] + kb + 64);
#pragma unroll
    for (int nt = 0; nt < 4; ++nt) bC[nt] = *(const bf16x8*)(wTe + bO[nt] + kb + 64);
#pragma unroll
    for (int mt = 0; mt < 4; ++mt)
#pragma unroll
      for (int nt = 0; nt < 4; ++nt)
        acc[mt][nt] = __builtin_amdgcn_mfma_f32_16x16x32_bf16(
            aN[mt], bN[nt], acc[mt][nt], 0, 0, 0);
  }
  // epilogue: C/D layout col=lane&15, row=(lane>>4)*4+reg [m89]
  int rq = lane >> 4;
  float bias[4];
#pragma unroll
  for (int nt = 0; nt < 4; ++nt)
    bias[nt] = eb[e * 1024 + n0 + wn * 64 + nt * 16 + lrow];
  u16* yb = ybuf + ((size_t)(e * SEG + m0)) * 1024 + n0 + wn * 64 + lrow;
#pragma unroll
  for (int mt = 0; mt < 4; ++mt) {
#pragma unroll
    for (int r = 0; r < 4; ++r) {
      int ml = wm * 64 + mt * 16 + rq * 4 + r;
      u16* row = yb + (size_t)ml * 1024;
#pragma unroll
      for (int nt = 0; nt < 4; ++nt)
        row[nt * 16] = f32_to_bf16(acc[mt][nt][r] + bias[nt]);
    }
  }
}

// ---------------------------------------------------------------------------
// Kernel 3: combine. out[t] = w0*ybuf[idx0] + w1*ybuf[idx1]  (pure BW).
// ---------------------------------------------------------------------------
__global__ __launch_bounds__(256) void combine_kernel(
    const u16* __restrict__ ybuf, const int* __restrict__ revIdx,
    const float* __restrict__ revW, float* __restrict__ out) {
  int tid = threadIdx.x, lane = tid & 63, wv = tid >> 6;
  for (int it = 0; it < 4; ++it) {
    int t  = blockIdx.x * 16 + wv * 4 + it;
    int i0 = revIdx[t * 2], i1 = revIdx[t * 2 + 1];
    float w0 = revW[t * 2], w1 = revW[t * 2 + 1];
    float o[16];
#pragma unroll
    for (int k = 0; k < 16; ++k) o[k] = 0.f;
    if (i0 >= 0) {
      const u16x8* y = (const u16x8*)(ybuf + (size_t)i0 * 1024);
#pragma unroll
      for (int jj = 0; jj < 2; ++jj) {
        u16x8 v = y[lane + 64 * jj];
#pragma unroll
        for (int k = 0; k < 8; ++k) o[jj * 8 + k] += w0 * bf16_to_f32(v[k]);
      }
    }
    if (i1 >= 0) {
      const u16x8* y = (const u16x8*)(ybuf + (size_t)i1 * 1024);
#pragma unroll
      for (int jj = 0; jj < 2; ++jj) {
        u16x8 v = y[lane + 64 * jj];
#pragma unroll
        for (int k = 0; k < 8; ++k) o[jj * 8 + k] += w1 * bf16_to_f32(v[k]);
      }
    }
    f32x4* o4 = (f32x4*)(out + (size_t)t * 1024);
#pragma unroll
    for (int jj = 0; jj < 2; ++jj)
#pragma unroll
      for (int h = 0; h < 2; ++h) {
        f32x4 vv = {o[jj * 8 + h * 4], o[jj * 8 + h * 4 + 1],
                    o[jj * 8 + h * 4 + 2], o[jj * 8 + h * 4 + 3]};
        o4[2 * (lane + 64 * jj) + h] = vv;
      }
  }
}

// ---------------------------------------------------------------------------
// Workspace layout (bytes), total ~64.2 MiB:
//   [0, 4096)        : int cnt[8*32] (one counter per 128B line)
//   [4096, +64K)     : tokList  8*2048 int (combined per-expert lists)
//   [+64K)           : revIdx   8192*2 int
//   [+64K)           : revW     8192*2 float
//   [+16M)           : xb   bf16 [8192][1024]
//   [+16M)           : wT   bf16 [8][1024][1024]
//   [+33.5M)         : ybuf bf16 [8*2048][1024]   (also absorbs over-reads)
// ---------------------------------------------------------------------------
extern "C" void kernel_launch(void* const* d_in, const int* in_sizes, int n_in,
                              void* d_out, int out_size, void* d_ws, size_t ws_size,
                              hipStream_t stream) {
  const float* x  = (const float*)d_in[0];
  const float* gw = (const float*)d_in[1];
  const float* gb = (const float*)d_in[2];
  const float* ew = (const float*)d_in[3];
  const float* eb = (const float*)d_in[4];
  float* out = (float*)d_out;
  char* ws = (char*)d_ws;
  int*   cnt     = (int*)ws;
  int*   tokList = (int*)(ws + 4096);
  int*   revIdx  = (int*)(ws + 4096 + 65536);
  float* revW    = (float*)(ws + 4096 + 131072);
  u16*   xb      = (u16*)(ws + 200704);
  u16*   wT      = (u16*)(ws + 200704 + 16777216);
  u16*   ybuf    = (u16*)(ws + 200704 + 33554432);

  hipMemsetAsync(cnt, 0, 4096, stream);
  prep_kernel<<<2560, 256, 0, stream>>>(x, gw, gb, ew, xb, wT, cnt, tokList,
                                        revIdx, revW);
  moe_gemm<<<dim3(8, 8, 16), 256, 0, stream>>>(xb, wT, cnt, tokList, eb, ybuf);
  combine_kernel<<<512, 256, 0, stream>>>(ybuf, revIdx, revW, out);
}

// Round 7
// 209.609 us; speedup vs baseline: 1.2040x; 1.2040x over previous
//
#include <hip/hip_runtime.h>
#include <hip/hip_bf16.h>
#include <stdint.h>

#define T_TOKENS 8192
#define D_DIM    1024
#define NE       10
#define NT       8
#define SEG      2048   // padded per-expert list capacity (actual ~1638, sigma~38)

typedef unsigned short u16;
typedef __attribute__((ext_vector_type(8))) __bf16 bf16x8;
typedef __attribute__((ext_vector_type(4))) float  f32x4;
typedef __attribute__((ext_vector_type(8))) unsigned short u16x8;

static __device__ __forceinline__ u16 f32_to_bf16(float f) {
  union { float f; uint32_t u; } v; v.f = f;
  uint32_t u = v.u;
  return (u16)((u + 0x7fffu + ((u >> 16) & 1u)) >> 16);
}
static __device__ __forceinline__ float bf16_to_f32(u16 u) {
  union { uint32_t u; float f; } v; v.u = ((uint32_t)u) << 16; return v.f;
}

// Fragment-major ("packed") operand layout, per expert, per 16-row group g:
//   elem(g, k, row) at  g*16384 + (k/8)*128 + row*8 + k%8      (u16 elems)
// A 16x16x32 MFMA fragment for group g, k-block kb (32 k) is then the
// contiguous 1KB at g*16384 + kb*512 + lane*8  — fully coalesced per wave.
// (R6's direct-from-global failed on 16-segment scatter; this fixes it.)

// ---------------------------------------------------------------------------
// Kernel 1: prep = gate + B-pack-transpose fused.
// blockIdx.x < 512: gate (16 tokens/block). Else: 64x64 tile of W[e][k][n]
// fp32 -> Bp fragment-major bf16 (e = tb&7 so transpose blocks are XCD-
// affine with the gemm's expert mapping).
// Gate gws LDS: padded 1-f32x4-per-8-lanes -> conflict-free 16B/lane reads
// (R5's unpadded version was 8-way conflicted).
// ---------------------------------------------------------------------------
union PrepShared {
  struct { f32x4 g4[NE * 4 * 71]; float gbs[NE]; int se[32]; float swt[32]; } g;
  struct { float tile[64][65]; } t;
};

__global__ __launch_bounds__(256) void prep_kernel(
    const float* __restrict__ x, const float* __restrict__ gw,
    const float* __restrict__ gb, const float* __restrict__ W,
    u16* __restrict__ Bp,
    int* __restrict__ cnt, int* __restrict__ tokList,
    int* __restrict__ revIdx, float* __restrict__ revW) {
  __shared__ PrepShared sh;
  int tid = threadIdx.x;

  if (blockIdx.x >= 512) {
    // ---- B-pack role ----
    int tb = blockIdx.x - 512;
    int e   = tb & 7;
    int rem = tb >> 3;
    int k0 = (rem >> 4) * 64;
    int n0 = (rem & 15) * 64;
    int c  = tid & 63;
    int r0 = tid >> 6;
    const float* We = W + ((size_t)e << 20);
#pragma unroll
    for (int rr = 0; rr < 16; ++rr) {
      int r = rr * 4 + r0;
      sh.t.tile[c][r] = We[(size_t)(k0 + r) * 1024 + n0 + c];  // coalesced read
    }
    __syncthreads();
    u16* Bpe = Bp + ((size_t)e << 20);
#pragma unroll
    for (int rr = 0; rr < 16; ++rr) {
      int n  = rr * 4 + r0;
      int np = n0 + n;          // output col (B row in B^T sense)
      int kp = k0 + c;          // k index
      // fragment-major: group np>>4, chunk kp>>3, row np&15, j kp&7
      Bpe[((np >> 4) * 16384) + ((kp >> 3) * 128) + ((np & 15) * 8) + (kp & 7)]
          = f32_to_bf16(sh.t.tile[n][c]);
    }
    return;
  }

  // ---- gate role: top-2 (strict > scan = lax.top_k tie-break) ----
  {
    const f32x4* g4 = (const f32x4*)gw;
    for (int u = tid; u < NE * 256; u += 256) {
      int e = u >> 8, r = u & 255, jj = r >> 6, ln = r & 63;
      sh.g.g4[e * 284 + jj * 71 + ln + (ln >> 3)] = g4[u];
    }
  }
  if (tid < NE) sh.g.gbs[tid] = gb[tid];
  __syncthreads();
  int lane = tid & 63;
  int wv   = tid >> 6;
  for (int it = 0; it < 4; ++it) {
    int slot = wv * 4 + it;
    int t = blockIdx.x * 16 + slot;
    const f32x4* xr4 = (const f32x4*)(x + (size_t)t * D_DIM);
    f32x4 xv[4];
#pragma unroll
    for (int jj = 0; jj < 4; ++jj) xv[jj] = xr4[lane + 64 * jj];
    float logit[NE];
#pragma unroll
    for (int e = 0; e < NE; ++e) {
      float a = 0.f;
#pragma unroll
      for (int jj = 0; jj < 4; ++jj) {
        f32x4 gv = sh.g.g4[e * 284 + jj * 71 + lane + (lane >> 3)];  // pad: 0-conflict
#pragma unroll
        for (int k = 0; k < 4; ++k) a = fmaf(xv[jj][k], gv[k], a);
      }
#pragma unroll
      for (int off = 32; off >= 1; off >>= 1) a += __shfl_xor(a, off);
      logit[e] = a + sh.g.gbs[e];
    }
    float mx = logit[0];
#pragma unroll
    for (int e = 1; e < NE; ++e) mx = fmaxf(mx, logit[e]);
    float p[NE]; float s = 0.f;
#pragma unroll
    for (int e = 0; e < NE; ++e) { p[e] = expf(logit[e] - mx); s += p[e]; }
    int e0 = 0; float b0 = p[0];
#pragma unroll
    for (int e = 1; e < NE; ++e) if (p[e] > b0) { b0 = p[e]; e0 = e; }
    int e1 = -1; float b1 = -1.f;
#pragma unroll
    for (int e = 0; e < NE; ++e) if (e != e0 && p[e] > b1) { b1 = p[e]; e1 = e; }
    float w0 = b0 / s, w1 = b1 / s;
    float tw0 = (e0 < NT) ? w0 : 0.f;
    float tw1 = (e1 < NT) ? w1 : 0.f;
    float denom = tw0 + tw1;
    float nw0 = 0.f, nw1 = 0.f;
    if (denom > 0.f) { nw0 = tw0 / denom; nw1 = tw1 / denom; }
    if (lane == 0) {
      sh.g.se[slot * 2]     = (e0 < NT) ? e0 : -1;  sh.g.swt[slot * 2]     = nw0;
      sh.g.se[slot * 2 + 1] = (e1 < NT) ? e1 : -1;  sh.g.swt[slot * 2 + 1] = nw1;
      if (e0 >= NT) { revIdx[t * 2]     = -1; revW[t * 2]     = 0.f; }
      if (e1 >= NT) { revIdx[t * 2 + 1] = -1; revW[t * 2 + 1] = 0.f; }
    }
  }
  __syncthreads();
  // compaction: thread e<8 scans 32 (token,slot) entries; one padded atomic.
  if (tid < NT) {
    int e = tid, c = 0;
    for (int i = 0; i < 32; ++i) c += (sh.g.se[i] == e);
    if (c > 0) {
      int base = atomicAdd(&cnt[e * 32], c);
      int j = 0;
      for (int i = 0; i < 32; ++i) {
        if (sh.g.se[i] == e) {
          int tt  = blockIdx.x * 16 + (i >> 1);
          int pos = base + j;
          tokList[e * SEG + pos]   = tt;
          revIdx[tt * 2 + (i & 1)] = e * SEG + pos;
          revW[tt * 2 + (i & 1)]   = sh.g.swt[i];
          ++j;
        }
      }
    }
  }
}

// ---------------------------------------------------------------------------
// Kernel 2: pack A. Gathers token rows (fp32 x) into per-expert fragment-
// major bf16 Ap. Reads: 16 tokens x 128B contiguous per instr-pair (full
// lines). Writes: contiguous 1KB/wave. grid (e, mtile, k-half); e fastest ->
// XCD-affine with gemm (Ap lands in expert's XCD L2).
// ---------------------------------------------------------------------------
__global__ __launch_bounds__(256) void pack_a(
    const float* __restrict__ x, const int* __restrict__ cnt,
    const int* __restrict__ tokList, u16* __restrict__ Ap) {
  int e = blockIdx.x, mt = blockIdx.y, half = blockIdx.z;
  int c = cnt[e * 32];
  if (mt * 128 >= c) return;
  int tid = threadIdx.x, lane = tid & 63, wv = tid >> 6;
  int q = lane >> 4, r16 = lane & 15;
  u16* Ape = Ap + ((size_t)e * SEG) * 1024;
#pragma unroll
  for (int gl = 0; gl < 2; ++gl) {
    int g = mt * 8 + wv * 2 + gl;
    int p = g * 16 + r16;
    if (p >= c) continue;                    // tail lanes skip (leave poison)
    int t = tokList[e * SEG + p];
    const float* xr = x + (size_t)t * 1024;
    u16* dst = Ape + (size_t)g * 16384 + r16 * 8;
    for (int cc = half * 16; cc < half * 16 + 16; ++cc) {
      int chunk = cc * 4 + q;                // k-chunk 0..127
      f32x4 v0 = *(const f32x4*)(xr + chunk * 8);
      f32x4 v1 = *(const f32x4*)(xr + chunk * 8 + 4);
      u16x8 pk;
#pragma unroll
      for (int k = 0; k < 4; ++k) { pk[k] = f32_to_bf16(v0[k]); pk[4 + k] = f32_to_bf16(v1[k]); }
      *(u16x8*)(dst + chunk * 128) = pk;     // wave: contiguous 1KB
    }
  }
}

// ---------------------------------------------------------------------------
// Kernel 3: per-expert GEMM, packed operands, NO LDS, NO barriers.
// Every fragment load is a coalesced 1KB/wave global_load_dwordx4 from the
// expert's XCD-resident L2 (grid x=expert). Register double-buffer gives one
// k-block of lookahead; 12+ waves/CU (no LDS limit) hide the rest.
// Final prefetch over-reads <=1KB past a group (next group / adjacent ws
// region for the very last) — never consumed.
// Epilogue: raw (acc+bias) -> bf16 ybuf[e*SEG+pos], plain stores, no races.
// ---------------------------------------------------------------------------
__global__ __launch_bounds__(256) void moe_gemm(
    const u16* __restrict__ Ap, const u16* __restrict__ Bp,
    const int* __restrict__ cnt, const float* __restrict__ eb,
    u16* __restrict__ ybuf) {
  int e  = blockIdx.x;
  int c  = cnt[e * 32];
  int m0 = blockIdx.z * 128;
  if (m0 >= c) return;
  int n0 = blockIdx.y * 128;
  int tid = threadIdx.x;
  int lane = tid & 63;
  int wv   = tid >> 6;
  int wm = wv >> 1, wn = wv & 1;
  const u16* Ape = Ap + ((size_t)e * SEG) * 1024;
  const u16* Bpe = Bp + ((size_t)e << 20);
  int aO[4], bO[4];
#pragma unroll
  for (int mt = 0; mt < 4; ++mt)
    aO[mt] = (blockIdx.z * 8 + wm * 4 + mt) * 16384 + lane * 8;
#pragma unroll
  for (int nt = 0; nt < 4; ++nt)
    bO[nt] = (blockIdx.y * 8 + wn * 4 + nt) * 16384 + lane * 8;

  f32x4 acc[4][4];
#pragma unroll
  for (int i = 0; i < 4; ++i)
#pragma unroll
    for (int j = 0; j < 4; ++j) acc[i][j] = (f32x4){0.f, 0.f, 0.f, 0.f};

  bf16x8 aC[4], bC[4], aN[4], bN[4];
#pragma unroll
  for (int mt = 0; mt < 4; ++mt) aC[mt] = *(const bf16x8*)(Ape + aO[mt]);
#pragma unroll
  for (int nt = 0; nt < 4; ++nt) bC[nt] = *(const bf16x8*)(Bpe + bO[nt]);

#pragma unroll 1
  for (int kb = 0; kb < 16384; kb += 1024) {   // elem units; 512 per k-block
    // phase 0: prefetch kb+512 into N, compute on C (@ kb)
#pragma unroll
    for (int mt = 0; mt < 4; ++mt) aN[mt] = *(const bf16x8*)(Ape + aO[mt] + kb + 512);
#pragma unroll
    for (int nt = 0; nt < 4; ++nt) bN[nt] = *(const bf16x8*)(Bpe + bO[nt] + kb + 512);
#pragma unroll
    for (int mt = 0; mt < 4; ++mt)
#pragma unroll
      for (int nt = 0; nt < 4; ++nt)
        acc[mt][nt] = __builtin_amdgcn_mfma_f32_16x16x32_bf16(
            aC[mt], bC[nt], acc[mt][nt], 0, 0, 0);
    // phase 1: prefetch kb+1024 into C (last iter over-reads, discarded),
    // compute on N (@ kb+512)
#pragma unroll
    for (int mt = 0; mt < 4; ++mt) aC[mt] = *(const bf16x8*)(Ape + aO[mt] + kb + 1024);
#pragma unroll
    for (int nt = 0; nt < 4; ++nt) bC[nt] = *(const bf16x8*)(Bpe + bO[nt] + kb + 1024);
#pragma unroll
    for (int mt = 0; mt < 4; ++mt)
#pragma unroll
      for (int nt = 0; nt < 4; ++nt)
        acc[mt][nt] = __builtin_amdgcn_mfma_f32_16x16x32_bf16(
            aN[mt], bN[nt], acc[mt][nt], 0, 0, 0);
  }
  // epilogue: C/D layout col=lane&15, row=(lane>>4)*4+reg [m89]
  int lrow = lane & 15;
  int rq   = lane >> 4;
  float bias[4];
#pragma unroll
  for (int nt = 0; nt < 4; ++nt)
    bias[nt] = eb[e * 1024 + n0 + wn * 64 + nt * 16 + lrow];
  u16* yb = ybuf + ((size_t)(e * SEG + m0)) * 1024 + n0 + wn * 64 + lrow;
#pragma unroll
  for (int mt = 0; mt < 4; ++mt) {
#pragma unroll
    for (int r = 0; r < 4; ++r) {
      int ml = wm * 64 + mt * 16 + rq * 4 + r;
      if (m0 + ml < c) {
        u16* row = yb + (size_t)ml * 1024;
#pragma unroll
        for (int nt = 0; nt < 4; ++nt)
          row[nt * 16] = f32_to_bf16(acc[mt][nt][r] + bias[nt]);
      }
    }
  }
}

// ---------------------------------------------------------------------------
// Kernel 4: combine. out[t] = w0*ybuf[idx0] + w1*ybuf[idx1]  (pure BW).
// ---------------------------------------------------------------------------
__global__ __launch_bounds__(256) void combine_kernel(
    const u16* __restrict__ ybuf, const int* __restrict__ revIdx,
    const float* __restrict__ revW, float* __restrict__ out) {
  int tid = threadIdx.x, lane = tid & 63, wv = tid >> 6;
  for (int it = 0; it < 4; ++it) {
    int t  = blockIdx.x * 16 + wv * 4 + it;
    int i0 = revIdx[t * 2], i1 = revIdx[t * 2 + 1];
    float w0 = revW[t * 2], w1 = revW[t * 2 + 1];
    float o[16];
#pragma unroll
    for (int k = 0; k < 16; ++k) o[k] = 0.f;
    if (i0 >= 0) {
      const u16x8* y = (const u16x8*)(ybuf + (size_t)i0 * 1024);
#pragma unroll
      for (int jj = 0; jj < 2; ++jj) {
        u16x8 v = y[lane + 64 * jj];
#pragma unroll
        for (int k = 0; k < 8; ++k) o[jj * 8 + k] += w0 * bf16_to_f32(v[k]);
      }
    }
    if (i1 >= 0) {
      const u16x8* y = (const u16x8*)(ybuf + (size_t)i1 * 1024);
#pragma unroll
      for (int jj = 0; jj < 2; ++jj) {
        u16x8 v = y[lane + 64 * jj];
#pragma unroll
        for (int k = 0; k < 8; ++k) o[jj * 8 + k] += w1 * bf16_to_f32(v[k]);
      }
    }
    f32x4* o4 = (f32x4*)(out + (size_t)t * 1024);
#pragma unroll
    for (int jj = 0; jj < 2; ++jj)
#pragma unroll
      for (int h = 0; h < 2; ++h) {
        f32x4 vv = {o[jj * 8 + h * 4], o[jj * 8 + h * 4 + 1],
                    o[jj * 8 + h * 4 + 2], o[jj * 8 + h * 4 + 3]};
        o4[2 * (lane + 64 * jj) + h] = vv;
      }
  }
}

// ---------------------------------------------------------------------------
// Workspace layout (bytes), total ~84.1 MB:
//   [0, 4096)        : int cnt[8*32] (one counter per 128B line)
//   [4096, +64K)     : tokList  8*2048 int
//   [+64K)           : revIdx   8192*2 int
//   [+64K)           : revW     8192*2 float
//   [200704)         : Ap  bf16 [8][2048 rows] fragment-major  (33.5 MB)
//   [+33.5M)         : Bp  bf16 [8][1024 cols] fragment-major  (16.8 MB)
//   [+16.8M)         : ybuf bf16 [8*2048][1024]                (33.5 MB)
//   (gemm's final 1KB prefetch over-read past Ap/Bp lands in the adjacent
//    region and is discarded)
// ---------------------------------------------------------------------------
extern "C" void kernel_launch(void* const* d_in, const int* in_sizes, int n_in,
                              void* d_out, int out_size, void* d_ws, size_t ws_size,
                              hipStream_t stream) {
  const float* x  = (const float*)d_in[0];
  const float* gw = (const float*)d_in[1];
  const float* gb = (const float*)d_in[2];
  const float* ew = (const float*)d_in[3];
  const float* eb = (const float*)d_in[4];
  float* out = (float*)d_out;
  char* ws = (char*)d_ws;
  int*   cnt     = (int*)ws;
  int*   tokList = (int*)(ws + 4096);
  int*   revIdx  = (int*)(ws + 4096 + 65536);
  float* revW    = (float*)(ws + 4096 + 131072);
  u16*   Ap      = (u16*)(ws + 200704);
  u16*   Bp      = (u16*)(ws + 200704 + 33554432);
  u16*   ybuf    = (u16*)(ws + 200704 + 33554432 + 16777216);

  hipMemsetAsync(cnt, 0, 4096, stream);
  prep_kernel<<<2560, 256, 0, stream>>>(x, gw, gb, ew, Bp, cnt, tokList,
                                        revIdx, revW);
  pack_a<<<dim3(8, 16, 2), 256, 0, stream>>>(x, cnt, tokList, Ap);
  moe_gemm<<<dim3(8, 8, 16), 256, 0, stream>>>(Ap, Bp, cnt, eb, ybuf);
  combine_kernel<<<512, 256, 0, stream>>>(ybuf, revIdx, revW, out);
}